// Round 7
// baseline (140.866 us; speedup 1.0000x reference)
//
#include <hip/hip_runtime.h>

typedef _Float16 f16x8 __attribute__((ext_vector_type(8)));
typedef float f32x4 __attribute__((ext_vector_type(4)));

#define B_  8
#define LQ  2048
#define LC  4096
#define DD  256

// async global->LDS, 16B per lane. LDS dest is wave-uniform base + lane*16.
__device__ __forceinline__ void gload_lds16(const void* g, void* l) {
    __builtin_amdgcn_global_load_lds(
        (const __attribute__((address_space(1))) unsigned int*)g,
        (__attribute__((address_space(3))) unsigned int*)l,
        16, 0, 0);
}

// Convert query only (context is consumed as f32 directly by gemm + out).
// Also zeroes `out` (out_kernel's atomicAdds run two kernels later).
__global__ __launch_bounds__(256)
void convert_q(const float* __restrict__ q, _Float16* __restrict__ qf,
               float* __restrict__ out) {
    if (blockIdx.x < 8) out[blockIdx.x * 256 + threadIdx.x] = 0.f;
    const int i = (blockIdx.x * 256 + threadIdx.x) * 8;   // 2048 blocks cover 8*2048*256
    const float4 a = *(const float4*)(q + i);
    const float4 c = *(const float4*)(q + i + 4);
    f16x8 o;
    o[0] = (_Float16)a.x; o[1] = (_Float16)a.y; o[2] = (_Float16)a.z; o[3] = (_Float16)a.w;
    o[4] = (_Float16)c.x; o[5] = (_Float16)c.y; o[6] = (_Float16)c.z; o[7] = (_Float16)c.w;
    *(f16x8*)(qf + i) = o;
}

// Phase-uniform counted-vmcnt pipeline (m218/m201-style), R7.
// Grid 256: bid&7 = batch (XCD affinity), mt = ctx tile of 128 rows.
// 8 waves = 2(wm: 64 ctx rows) x 4(wn: 64 q cols). BN=256 q per tile,
// 8 q-tiles per block. A (ctx f32) converted once into af[4][8] (resident).
//
// B stream: 64 units of 16KB = [256 q][32 k] f16, PAIR-INTERLEAVED layout:
// byte(q,k) = (q>>1)*128 + (q&1)*64 + (k>>3)*16 + (k&7)*2. Linear
// global_load_lds write and ds_read_b128 frag read are both bijective onto
// 1KB -> conflict-free, no XOR swizzle needed. Unit u = qt*8 + t*2 + kh
// lives in buffer (u+2)&7 (8 x 16KB = 128KB LDS).
//
// 32 phases (qt x t): {8 ds_read_b128; stage units 2v+4,2v+5; vmcnt(4);
// s_barrier; lgkmcnt(0); setprio(1); 32 MFMA; setprio(0)}. vmcnt(4) is
// uniform (in-flight = 2 landed-pending units + 2 just issued); drains to 0
// only in the last two phases. A-prologue: 8 f32 chunks through the same
// buffers with the R1-verified XOR layout + convert.
__global__ __launch_bounds__(512, 2)
void gemm_max_kernel(const _Float16* __restrict__ qf,
                     const float* __restrict__ ctx,
                     float* __restrict__ scores) {
    __shared__ __align__(16) char LB[8][16384];   // 128 KB
    __shared__ float red[4][128];

    const int bid = blockIdx.x;
    const int b   = bid & 7;     // XCD affinity: batch b -> XCD b
    const int mt  = bid >> 3;    // ctx tile 0..31

    const int tid  = threadIdx.x;
    const int lane = tid & 63;
    const int wave = tid >> 6;   // 0..7
    const int wm   = wave >> 2;  // ctx half (0..1) -> 64 rows
    const int wn   = wave & 3;   // q slot  (0..3) -> 64 cols
    const int quad = lane >> 4;
    const int l15  = lane & 15;

    const float*    Ag = ctx + ((size_t)b * LC + (size_t)mt * 128) * DD;
    const _Float16* Bg = qf  + (size_t)b * LQ * DD;

    // ---- A staging map (R1-verified XOR layout): chunk = [128 rows][32 f32],
    // 128B rows of 8 x 16B groups, g_glob = g_store ^ (row&7).
    const int a_row  = tid >> 3;          // per pass p: row = p*64 + a_row
    const int a_gg   = (tid & 7) ^ ((tid >> 3) & 7);

#define STAGE_A(j)                                                              \
    {                                                                           \
        _Pragma("unroll")                                                       \
        for (int p = 0; p < 2; ++p)                                             \
            gload_lds16(Ag + (size_t)(p * 64 + a_row) * DD + (j) * 32 + a_gg * 4, \
                        LB[j] + p * 8192 + tid * 16);                           \
    }

    // ---- B staging map (pair-interleaved): thread -> q row qb(+p*128), k kf_off
    const int qb     = ((tid >> 3) << 1) + ((tid >> 2) & 1);
    const int kf_off = (tid & 3) * 8;

#define STAGE_B(qt_, tt_, kh_, bufi)                                            \
    {                                                                           \
        const _Float16* _s = Bg + (size_t)((qt_) * 256 + qb) * DD               \
                             + (tt_) * 64 + (kh_) * 32 + kf_off;                \
        _Pragma("unroll")                                                       \
        for (int p = 0; p < 2; ++p)                                             \
            gload_lds16(_s + (size_t)p * 128 * DD,                              \
                        LB[bufi] + p * 8192 + tid * 16);                        \
    }

#define SYNCV(N)                                                                \
    {                                                                           \
        __builtin_amdgcn_sched_barrier(0);                                      \
        asm volatile("s_waitcnt vmcnt(" #N ")" ::: "memory");                   \
        __builtin_amdgcn_s_barrier();                                           \
        __builtin_amdgcn_sched_barrier(0);                                      \
    }

#define LGKM0                                                                   \
    {                                                                           \
        asm volatile("s_waitcnt lgkmcnt(0)" ::: "memory");                      \
        __builtin_amdgcn_sched_barrier(0);                                      \
    }

    f16x8 af[4][8];   // A fragments, resident (rows wm*64.., all K)
    f32x4 acc[4][4];
    float rm[4][4];

    // fill af[*][j] from f32 A chunk j in LB[j] (R1-verified)
#define FILL_A(j)                                                               \
    {                                                                           \
        _Pragma("unroll")                                                       \
        for (int mi = 0; mi < 4; ++mi) {                                        \
            const int row = wm * 64 + mi * 16 + l15;                            \
            const int p0  = (2 * quad) ^ (row & 7);                             \
            const int p1  = (2 * quad + 1) ^ (row & 7);                         \
            const f32x4 v0 = *(const f32x4*)(LB[j] + row * 128 + p0 * 16);      \
            const f32x4 v1 = *(const f32x4*)(LB[j] + row * 128 + p1 * 16);      \
            f16x8 o;                                                            \
            o[0] = (_Float16)v0[0]; o[1] = (_Float16)v0[1];                     \
            o[2] = (_Float16)v0[2]; o[3] = (_Float16)v0[3];                     \
            o[4] = (_Float16)v1[0]; o[5] = (_Float16)v1[1];                     \
            o[6] = (_Float16)v1[2]; o[7] = (_Float16)v1[3];                     \
            af[mi][j] = o;                                                      \
        }                                                                       \
    }

#pragma unroll
    for (int mi = 0; mi < 4; ++mi)
#pragma unroll
        for (int r = 0; r < 4; ++r) rm[mi][r] = -3.4e38f;
#pragma unroll
    for (int mi = 0; mi < 4; ++mi)
#pragma unroll
        for (int ni = 0; ni < 4; ++ni) acc[mi][ni] = (f32x4)0.0f;

    // ---- prologue: A chunks 0..7 -> bufs 0..7, all loads issued up front.
    STAGE_A(0); STAGE_A(1); STAGE_A(2); STAGE_A(3);
    STAGE_A(4); STAGE_A(5); STAGE_A(6); STAGE_A(7);
    SYNCV(14); FILL_A(0);
    SYNCV(12); FILL_A(1);
    SYNCV(10); FILL_A(2);
    SYNCV(8);  FILL_A(3);
    SYNCV(6);  FILL_A(4);
    SYNCV(4);  FILL_A(5);
    SYNCV(2);  FILL_A(6);
    SYNCV(0);  FILL_A(7);
    __syncthreads();                       // all FILL reads done; bufs free
    // stage B units 0..3 (qt0: t0/t1, kh0/1) -> bufs 2..5
    STAGE_B(0, 0, 0, 2); STAGE_B(0, 0, 1, 3);
    STAGE_B(0, 1, 0, 4); STAGE_B(0, 1, 1, 5);
    SYNCV(4);                              // units 0,1 landed; 2,3 in flight

    // ---- main: 8 q-tiles x 4 K-steps; phase v = qt*4 + t.
    // reads bufs (t*2+2)&7,(t*2+3)&7; stages units 2v+4,2v+5 -> (t*2+6)&7,(t*2+7)&7.
#pragma unroll 1
    for (int qt = 0; qt < 8; ++qt) {
#pragma unroll
        for (int t = 0; t < 4; ++t) {
            // -- ds-read this phase's 8 B fragments (2 ksl x 4 ni)
            f16x8 bfv[2][4];
#pragma unroll
            for (int ksl = 0; ksl < 2; ++ksl) {
                const char* bb = LB[(t * 2 + ksl + 2) & 7];
#pragma unroll
                for (int ni = 0; ni < 4; ++ni) {
                    const int ql = wn * 64 + ni * 16 + l15;
                    bfv[ksl][ni] = *(const f16x8*)(bb + (ql >> 1) * 128
                                                   + (ql & 1) * 64 + quad * 16);
                }
            }
            // -- stage units 2v+4, 2v+5
            if (t < 2) {
                STAGE_B(qt, t + 2, 0, (t * 2 + 6) & 7);
                STAGE_B(qt, t + 2, 1, (t * 2 + 7) & 7);
            } else if (qt < 7) {
                STAGE_B(qt + 1, t - 2, 0, (t * 2 + 6) & 7);
                STAGE_B(qt + 1, t - 2, 1, (t * 2 + 7) & 7);
            }
            // -- counted sync (drain only in the last two phases)
            if (qt == 7 && t >= 2) { SYNCV(0); }
            else                   { SYNCV(4); }
            LGKM0;
            // -- pure MFMA cluster
            __builtin_amdgcn_s_setprio(1);
#pragma unroll
            for (int ksl = 0; ksl < 2; ++ksl)
#pragma unroll
                for (int mi = 0; mi < 4; ++mi)
#pragma unroll
                    for (int ni = 0; ni < 4; ++ni)
                        acc[mi][ni] = __builtin_amdgcn_mfma_f32_16x16x32_f16(
                            af[mi][t * 2 + ksl], bfv[ksl][ni], acc[mi][ni], 0, 0, 0);
            __builtin_amdgcn_s_setprio(0);
        }
        // fold this q-tile into the running row max; reset acc
#pragma unroll
        for (int mi = 0; mi < 4; ++mi)
#pragma unroll
            for (int r = 0; r < 4; ++r) {
                rm[mi][r] = fmaxf(rm[mi][r],
                                  fmaxf(fmaxf(acc[mi][0][r], acc[mi][1][r]),
                                        fmaxf(acc[mi][2][r], acc[mi][3][r])));
                acc[mi][0][r] = 0.f; acc[mi][1][r] = 0.f;
                acc[mi][2][r] = 0.f; acc[mi][3][r] = 0.f;
            }
    }

    // ---- epilogue: reduce 16 col lanes, then the four wn slots
#pragma unroll
    for (int sh = 1; sh <= 8; sh <<= 1)
#pragma unroll
        for (int mi = 0; mi < 4; ++mi)
#pragma unroll
            for (int r = 0; r < 4; ++r)
                rm[mi][r] = fmaxf(rm[mi][r], __shfl_xor(rm[mi][r], sh, 64));

    if (l15 == 0) {
#pragma unroll
        for (int mi = 0; mi < 4; ++mi)
#pragma unroll
            for (int r = 0; r < 4; ++r)
                red[wn][wm * 64 + mi * 16 + quad * 4 + r] = rm[mi][r];
    }
    __syncthreads();
    if (tid < 128)
        scores[(size_t)b * LC + mt * 128 + tid] =
            fmaxf(fmaxf(red[0][tid], red[1][tid]),
                  fmaxf(red[2][tid], red[3][tid]));

#undef STAGE_A
#undef STAGE_B
#undef SYNCV
#undef LGKM0
#undef FILL_A
}

// Fused softmax-stats + weighted context sum. Each block recomputes M and the
// softmax denominator from the 4096 scores (16 KB, L2-hit, deterministic ->
// identical across blocks), then accumulates its 64-row chunk of
// out[b][d] = sum_c softmax(scores)[c] * ctx[b][c][d]   (ctx read as f32).
__global__ __launch_bounds__(256)
void out_kernel(const float* __restrict__ scores, const float* __restrict__ ctx,
                float* __restrict__ out) {
    const int ch   = blockIdx.x;   // 0..63
    const int b    = blockIdx.y;   // 0..7
    const int tid  = threadIdx.x;
    const int lane = tid & 63;
    const int wave = tid >> 6;
    __shared__ float smax[4];
    __shared__ float ssum[4];
    __shared__ float pl[64];

    const float* sb = scores + (size_t)b * LC;

    float sv[16];
    float lmax = -3.4e38f;
#pragma unroll
    for (int j = 0; j < 16; ++j) {
        sv[j] = sb[tid + j * 256];
        lmax  = fmaxf(lmax, sv[j]);
    }
    for (int sh = 1; sh < 64; sh <<= 1)
        lmax = fmaxf(lmax, __shfl_xor(lmax, sh, 64));
    if (lane == 0) smax[wave] = lmax;
    __syncthreads();
    const float M = fmaxf(fmaxf(smax[0], smax[1]), fmaxf(smax[2], smax[3]));

    float lsum = 0.f;
#pragma unroll
    for (int j = 0; j < 16; ++j)
        lsum += expf(sv[j] - M);
    for (int sh = 1; sh < 64; sh <<= 1)
        lsum += __shfl_xor(lsum, sh, 64);
    if (lane == 0) ssum[wave] = lsum;
    __syncthreads();
    const float inv = 1.f / (ssum[0] + ssum[1] + ssum[2] + ssum[3]);

    if (tid < 64) pl[tid] = expf(sb[ch * 64 + tid] - M) * inv;
    __syncthreads();

    const float* cb = ctx + ((size_t)b * LC + (size_t)ch * 64) * DD;
    float acc = 0.f;
#pragma unroll 8
    for (int i = 0; i < 64; ++i)
        acc += pl[i] * cb[(size_t)i * DD + tid];   // coalesced f32
    atomicAdd(&out[b * DD + tid], acc);
}

extern "C" void kernel_launch(void* const* d_in, const int* in_sizes, int n_in,
                              void* d_out, int out_size, void* d_ws, size_t ws_size,
                              hipStream_t stream) {
    const float* q   = (const float*)d_in[0];   // [8, 2048, 256] f32
    const float* ctx = (const float*)d_in[1];   // [8, 4096, 256] f32
    float* out = (float*)d_out;                 // [8, 1, 256] f32

    // ws layout (bytes):
    //   qf     @ 0        : 8*2048*256*2 = 8,388,608
    //   scores @ 8388608  : 8*4096*4     =   131,072
    char* ws = (char*)d_ws;
    _Float16* qf  = (_Float16*)(ws);
    float* scores = (float*)(ws + 8388608);

    convert_q<<<2048, 256, 0, stream>>>(q, qf, out);
    gemm_max_kernel<<<256, 512, 0, stream>>>(qf, ctx, scores);
    out_kernel<<<dim3(64, 8), 256, 0, stream>>>(scores, ctx, out);
}

// Round 8
// 128.766 us; speedup vs baseline: 1.0940x; 1.0940x over previous
//
#include <hip/hip_runtime.h>

typedef _Float16 f16x8 __attribute__((ext_vector_type(8)));
typedef float f32x4 __attribute__((ext_vector_type(4)));

#define B_  8
#define LQ  2048
#define LC  4096
#define DD  256

// async global->LDS, 16B per lane. LDS dest is wave-uniform base + lane*16.
__device__ __forceinline__ void gload_lds16(const void* g, void* l) {
    __builtin_amdgcn_global_load_lds(
        (const __attribute__((address_space(1))) unsigned int*)g,
        (__attribute__((address_space(3))) unsigned int*)l,
        16, 0, 0);
}

// Convert query only (context is consumed as f32 directly by gemm + out).
// Also zeroes `out` (out_kernel's atomicAdds run two kernels later).
__global__ __launch_bounds__(256)
void convert_q(const float* __restrict__ q, _Float16* __restrict__ qf,
               float* __restrict__ out) {
    if (blockIdx.x < 8) out[blockIdx.x * 256 + threadIdx.x] = 0.f;
    const int i = (blockIdx.x * 256 + threadIdx.x) * 8;   // 2048 blocks cover 8*2048*256
    const float4 a = *(const float4*)(q + i);
    const float4 c = *(const float4*)(q + i + 4);
    f16x8 o;
    o[0] = (_Float16)a.x; o[1] = (_Float16)a.y; o[2] = (_Float16)a.z; o[3] = (_Float16)a.w;
    o[4] = (_Float16)c.x; o[5] = (_Float16)c.y; o[6] = (_Float16)c.z; o[7] = (_Float16)c.w;
    *(f16x8*)(qf + i) = o;
}

// R8. Model fitted to R1-R7: gemm time = LDS-staged bytes per CU / ~11 B/cyc.
// All schedule variants were neutral because staging fill-rate is bytes-bound.
// So: cut staged bytes. (1) BM=256 with q-halved grid (16 ctx tiles x 2 qh x
// 8 b = 256 blocks): B staged/block 1MB -> 512KB. (2) A (ctx) skips LDS
// entirely: af[4][8] filled by direct global->VGPR f32x4 loads + in-reg cvt
// (fragment k-map = R4's verified LOADQ pattern; ctx tile is block-local,
// 256KB, so no R4-style L2 thrash). Staged bytes/CU: 1.13MB -> 0.5MB.
//
// B pipeline = R2's twice-verified chunk structure verbatim: 32 chunks of
// [128 q][64 k] f16, XOR-swizzled 16KB units, 4 buffers, counted vmcnt(4),
// depth-3 prefetch, one barrier per chunk. Waves: 4(wm: 64 ctx rows) x
// 2(wn: 64 q cols); per wave acc[4][4] (mi x ni), 32 MFMA/chunk.
__global__ __launch_bounds__(512, 2)
void gemm_max_kernel(const _Float16* __restrict__ qf,
                     const float* __restrict__ ctx,
                     float* __restrict__ scores) {
    __shared__ __align__(16) _Float16 Buf[4][8192];   // 4 x 16 KB
    __shared__ float red[2][256];

    const int bid = blockIdx.x;
    const int b   = bid & 7;          // XCD affinity: batch b -> XCD b
    const int mt  = (bid >> 3) & 15;  // ctx tile 0..15 (256 rows)
    const int qh  = bid >> 7;         // query half 0..1 (1024 q each)

    const int tid  = threadIdx.x;
    const int lane = tid & 63;
    const int wave = tid >> 6;   // 0..7
    const int wm   = wave >> 1;  // ctx slot (0..3) -> 64 rows each
    const int wn   = wave & 1;   // q slot   (0..1) -> 64 cols each
    const int quad = lane >> 4;
    const int l15  = lane & 15;

    const float*    Ag = ctx + ((size_t)b * LC + (size_t)mt * 256) * DD;
    const _Float16* Bg = qf  + ((size_t)b * LQ + (size_t)qh * 1024) * DD;

    // ---- B staging map (R2-verified): 512 threads x 16B x 2 passes = 16KB.
    // thread t -> row srow (+64 per pass), LDS group g_store, global group
    // g_glob = g_store ^ (row&7)   (row&7 == srow&7 since pass stride 64).
    const int srow    = tid >> 3;    // 0..63
    const int g_store = tid & 7;
    const int g_glob  = g_store ^ (srow & 7);

    // B chunk c (c = nt*4 + kc): q rows [nt*128, +128) of this half, k [kc*64, +64)
#define STAGE_B(c, bufi)                                                        \
    {                                                                           \
        const _Float16* _s = Bg + (size_t)((c) >> 2) * 128 * DD + ((c) & 3) * 64; \
        _Pragma("unroll")                                                       \
        for (int p = 0; p < 2; ++p)                                             \
            gload_lds16(_s + (size_t)(p * 64 + srow) * DD + g_glob * 8,         \
                        (char*)Buf[bufi] + p * 8192 + tid * 16);                \
    }

    // counted-vmcnt barrier. sched_barrier(0) pins compute/ds_reads on both
    // sides (rule 18: "memory" clobber alone does not order MFMA/ds_read).
#define SYNC(N)                                                                 \
    {                                                                           \
        __builtin_amdgcn_sched_barrier(0);                                      \
        asm volatile("s_waitcnt vmcnt(" #N ")" ::: "memory");                   \
        __builtin_amdgcn_s_barrier();                                           \
        __builtin_amdgcn_sched_barrier(0);                                      \
    }

    f16x8 af[4][8];   // A fragments: rows wm*64+mi*16+l15, k = j*32+quad*8+e
    f32x4 acc[4][4];
    float rm[4][4];

    // ---- A prologue: direct global->VGPR, convert in-register.
    // Element map == R4's verified LOADQ (l15 row, quad*8 k-octet).
#pragma unroll
    for (int mi = 0; mi < 4; ++mi) {
        const float* pr = Ag + (size_t)(wm * 64 + mi * 16 + l15) * DD + quad * 8;
#pragma unroll
        for (int j = 0; j < 8; ++j) {
            const f32x4 v0 = *(const f32x4*)(pr + j * 32);
            const f32x4 v1 = *(const f32x4*)(pr + j * 32 + 4);
            f16x8 o;
            o[0] = (_Float16)v0[0]; o[1] = (_Float16)v0[1];
            o[2] = (_Float16)v0[2]; o[3] = (_Float16)v0[3];
            o[4] = (_Float16)v1[0]; o[5] = (_Float16)v1[1];
            o[6] = (_Float16)v1[2]; o[7] = (_Float16)v1[3];
            af[mi][j] = o;
        }
    }
    // pin: all A loads retired before any STAGE_B issues -> exact vmcnt ledger
    __builtin_amdgcn_sched_barrier(0);
    asm volatile("s_waitcnt vmcnt(0)" ::: "memory");
    __builtin_amdgcn_sched_barrier(0);

#pragma unroll
    for (int mi = 0; mi < 4; ++mi) {
#pragma unroll
        for (int r = 0; r < 4; ++r) rm[mi][r] = -3.4e38f;
#pragma unroll
        for (int ni = 0; ni < 4; ++ni) acc[mi][ni] = (f32x4)0.0f;
    }

    // ---- B prologue: stage chunks 0..2 (6 loads/thread in flight)
    STAGE_B(0, 0); STAGE_B(1, 1); STAGE_B(2, 2);

    // ---- main: 8 q-tiles x 4 K-chunks. Iter c: SYNC (chunk c lands);
    // stage c+3; compute c. Ledger: entering iter c, outstanding = chunks
    // c..min(c+2,31) = 2 loads each -> wait 4/4/../4, then 2 (c=30), 0 (c=31).
#pragma unroll 1
    for (int nt = 0; nt < 8; ++nt) {
#pragma unroll
        for (int kc = 0; kc < 4; ++kc) {
            const int c = nt * 4 + kc;
            if (kc < 2)       { SYNC(4); }
            else if (kc == 2) { if (nt < 7) { SYNC(4); } else { SYNC(2); } }
            else              { if (nt < 7) { SYNC(4); } else { SYNC(0); } }

            if (c + 3 < 32) STAGE_B(c + 3, (c + 3) & 3);

            // ds-read this chunk's 8 B fragments (2 ksl x 4 ni)
            f16x8 bfv[2][4];
#pragma unroll
            for (int ksl = 0; ksl < 2; ++ksl)
#pragma unroll
                for (int ni = 0; ni < 4; ++ni) {
                    const int row = wn * 64 + ni * 16 + l15;   // q row 0..127
                    const int pos = (ksl * 4 + quad) ^ (row & 7);
                    bfv[ksl][ni] =
                        *(const f16x8*)((const char*)Buf[kc] + row * 128 + pos * 16);
                }
            __builtin_amdgcn_s_setprio(1);
#pragma unroll
            for (int ksl = 0; ksl < 2; ++ksl)
#pragma unroll
                for (int mi = 0; mi < 4; ++mi)
#pragma unroll
                    for (int ni = 0; ni < 4; ++ni)
                        acc[mi][ni] = __builtin_amdgcn_mfma_f32_16x16x32_f16(
                            af[mi][kc * 2 + ksl], bfv[ksl][ni], acc[mi][ni], 0, 0, 0);
            __builtin_amdgcn_s_setprio(0);
        }
        // fold q-tile into running row max; reset acc
#pragma unroll
        for (int mi = 0; mi < 4; ++mi)
#pragma unroll
            for (int r = 0; r < 4; ++r) {
                rm[mi][r] = fmaxf(rm[mi][r],
                                  fmaxf(fmaxf(acc[mi][0][r], acc[mi][1][r]),
                                        fmaxf(acc[mi][2][r], acc[mi][3][r])));
                acc[mi][0][r] = 0.f; acc[mi][1][r] = 0.f;
                acc[mi][2][r] = 0.f; acc[mi][3][r] = 0.f;
            }
    }

    // ---- epilogue: reduce over the 16 q-col lanes, then the two wn slots
#pragma unroll
    for (int sh = 1; sh <= 8; sh <<= 1)
#pragma unroll
        for (int mi = 0; mi < 4; ++mi)
#pragma unroll
            for (int r = 0; r < 4; ++r)
                rm[mi][r] = fmaxf(rm[mi][r], __shfl_xor(rm[mi][r], sh, 64));

    if (l15 == 0) {
#pragma unroll
        for (int mi = 0; mi < 4; ++mi)
#pragma unroll
            for (int r = 0; r < 4; ++r)
                red[wn][wm * 64 + mi * 16 + quad * 4 + r] = rm[mi][r];
    }
    __syncthreads();
    if (tid < 256)
        scores[(size_t)qh * (B_ * LC) + (size_t)b * LC + mt * 256 + tid] =
            fmaxf(red[0][tid], red[1][tid]);

#undef STAGE_B
#undef SYNC
}

// Fused softmax-stats + weighted context sum. scores come in two q-half
// buffers; final score = fmax of the two. Each block recomputes M and the
// softmax denominator (16 KB, L2-hit, deterministic -> identical across
// blocks), then accumulates its 64-row chunk of
// out[b][d] = sum_c softmax(scores)[c] * ctx[b][c][d]   (ctx read as f32).
__global__ __launch_bounds__(256)
void out_kernel(const float* __restrict__ scores, const float* __restrict__ ctx,
                float* __restrict__ out) {
    const int ch   = blockIdx.x;   // 0..63
    const int b    = blockIdx.y;   // 0..7
    const int tid  = threadIdx.x;
    const int lane = tid & 63;
    const int wave = tid >> 6;
    __shared__ float smax[4];
    __shared__ float ssum[4];
    __shared__ float pl[64];

    const float* sb0 = scores + (size_t)b * LC;
    const float* sb1 = sb0 + (size_t)B_ * LC;

    float sv[16];
    float lmax = -3.4e38f;
#pragma unroll
    for (int j = 0; j < 16; ++j) {
        const int c = tid + j * 256;
        sv[j] = fmaxf(sb0[c], sb1[c]);
        lmax  = fmaxf(lmax, sv[j]);
    }
    for (int sh = 1; sh < 64; sh <<= 1)
        lmax = fmaxf(lmax, __shfl_xor(lmax, sh, 64));
    if (lane == 0) smax[wave] = lmax;
    __syncthreads();
    const float M = fmaxf(fmaxf(smax[0], smax[1]), fmaxf(smax[2], smax[3]));

    float lsum = 0.f;
#pragma unroll
    for (int j = 0; j < 16; ++j)
        lsum += expf(sv[j] - M);
    for (int sh = 1; sh < 64; sh <<= 1)
        lsum += __shfl_xor(lsum, sh, 64);
    if (lane == 0) ssum[wave] = lsum;
    __syncthreads();
    const float inv = 1.f / (ssum[0] + ssum[1] + ssum[2] + ssum[3]);

    if (tid < 64) {
        const int c = ch * 64 + tid;
        pl[tid] = expf(fmaxf(sb0[c], sb1[c]) - M) * inv;
    }
    __syncthreads();

    const float* cb = ctx + ((size_t)b * LC + (size_t)ch * 64) * DD;
    float acc = 0.f;
#pragma unroll 8
    for (int i = 0; i < 64; ++i)
        acc += pl[i] * cb[(size_t)i * DD + tid];   // coalesced f32
    atomicAdd(&out[b * DD + tid], acc);
}

extern "C" void kernel_launch(void* const* d_in, const int* in_sizes, int n_in,
                              void* d_out, int out_size, void* d_ws, size_t ws_size,
                              hipStream_t stream) {
    const float* q   = (const float*)d_in[0];   // [8, 2048, 256] f32
    const float* ctx = (const float*)d_in[1];   // [8, 4096, 256] f32
    float* out = (float*)d_out;                 // [8, 1, 256] f32

    // ws layout (bytes):
    //   qf     @ 0        : 8*2048*256*2 = 8,388,608
    //   scores @ 8388608  : 2*8*4096*4   =   262,144   (two q-half buffers)
    char* ws = (char*)d_ws;
    _Float16* qf  = (_Float16*)(ws);
    float* scores = (float*)(ws + 8388608);

    convert_q<<<2048, 256, 0, stream>>>(q, qf, out);
    gemm_max_kernel<<<256, 512, 0, stream>>>(qf, ctx, scores);
    out_kernel<<<dim3(64, 8), 256, 0, stream>>>(scores, ctx, out);
}

// Round 9
// 120.569 us; speedup vs baseline: 1.1683x; 1.0680x over previous
//
#include <hip/hip_runtime.h>

typedef _Float16 f16x8 __attribute__((ext_vector_type(8)));
typedef float f32x4 __attribute__((ext_vector_type(4)));

#define B_  8
#define LQ  2048
#define LC  4096
#define DD  256

// async global->LDS, 16B per lane. LDS dest is wave-uniform base + lane*16.
__device__ __forceinline__ void gload_lds16(const void* g, void* l) {
    __builtin_amdgcn_global_load_lds(
        (const __attribute__((address_space(1))) unsigned int*)g,
        (__attribute__((address_space(3))) unsigned int*)l,
        16, 0, 0);
}

// Convert query only (context is consumed as f32 directly by gemm + out).
// Also zeroes `out` (out_kernel's atomicAdds run two kernels later).
__global__ __launch_bounds__(256)
void convert_q(const float* __restrict__ q, _Float16* __restrict__ qf,
               float* __restrict__ out) {
    if (blockIdx.x < 8) out[blockIdx.x * 256 + threadIdx.x] = 0.f;
    const int i = (blockIdx.x * 256 + threadIdx.x) * 8;   // 2048 blocks cover 8*2048*256
    const float4 a = *(const float4*)(q + i);
    const float4 c = *(const float4*)(q + i + 4);
    f16x8 o;
    o[0] = (_Float16)a.x; o[1] = (_Float16)a.y; o[2] = (_Float16)a.z; o[3] = (_Float16)a.w;
    o[4] = (_Float16)c.x; o[5] = (_Float16)c.y; o[6] = (_Float16)c.z; o[7] = (_Float16)c.w;
    *(f16x8*)(qf + i) = o;
}

// R9. Model fitted to R1-R8: gemm time = total 16B VMEM requests per CU x
// ~1.4-1.8 cyc (per-CU request-rate bound; matches m13's 1.56 cyc/req).
// Sync/occupancy/conflicts were all neutral because the TA request pipe is
// the serial resource. R8's A-direct loads cost 64 req/thread (wn-duplicated);
// staging A once through LDS costs 32. This kernel = R8 with ONLY the A
// prologue changed to the R2-verified LDS chunk pipeline:
//   16 A-chunks of [128 rows][32 k f32] (16KB, XOR layout) through the same
//   4 buffers; uniform SYNC(4) ledger hands off directly into the B stream
//   (B0..B2 staged in A-slots 13..15; outstanding is always 6 loads).
// Requests/thread: 32 (A) + 64 (B) = 96 vs R8's 128.
//
// Waves: 4(wm: 64 ctx rows) x 2(wn: 64 q cols); af[4][8] resident; B main
// loop, epilogue, scores/out scheme identical to R8 (twice-verified).
__global__ __launch_bounds__(512, 2)
void gemm_max_kernel(const _Float16* __restrict__ qf,
                     const float* __restrict__ ctx,
                     float* __restrict__ scores) {
    __shared__ __align__(16) _Float16 Buf[4][8192];   // 4 x 16 KB
    __shared__ float red[2][256];

    const int bid = blockIdx.x;
    const int b   = bid & 7;          // XCD affinity: batch b -> XCD b
    const int mt  = (bid >> 3) & 15;  // ctx tile 0..15 (256 rows)
    const int qh  = bid >> 7;         // query half 0..1 (1024 q each)

    const int tid  = threadIdx.x;
    const int lane = tid & 63;
    const int wave = tid >> 6;   // 0..7
    const int wm   = wave >> 1;  // ctx slot (0..3) -> 64 rows each
    const int wn   = wave & 1;   // q slot   (0..1) -> 64 cols each
    const int quad = lane >> 4;
    const int l15  = lane & 15;

    const float*    Ag = ctx + ((size_t)b * LC + (size_t)mt * 256) * DD;
    const _Float16* Bg = qf  + ((size_t)b * LQ + (size_t)qh * 1024) * DD;

    // staging map (R2-verified): 512 threads x 16B x 2 passes = 16KB chunk.
    // thread t -> row srow (+64 per pass), LDS group g_store, global group
    // g_glob = g_store ^ (row&7)   (row&7 == srow&7 since pass stride 64).
    const int srow    = tid >> 3;    // 0..63
    const int g_store = tid & 7;
    const int g_glob  = g_store ^ (srow & 7);

    // A chunk ac = h*8 + j: ctx rows [h*128, +128), k [j*32, +32) f32
#define STAGE_A(ac, bufi)                                                       \
    {                                                                           \
        const float* _a = Ag + (size_t)((ac) >> 3) * 128 * DD + ((ac) & 7) * 32; \
        _Pragma("unroll")                                                       \
        for (int p = 0; p < 2; ++p)                                             \
            gload_lds16(_a + (size_t)(p * 64 + srow) * DD + g_glob * 4,         \
                        (char*)Buf[bufi] + p * 8192 + tid * 16);                \
    }

    // B chunk c (c = nt*4 + kc): q rows [nt*128, +128) of this half, k [kc*64, +64)
#define STAGE_B(c, bufi)                                                        \
    {                                                                           \
        const _Float16* _s = Bg + (size_t)((c) >> 2) * 128 * DD + ((c) & 3) * 64; \
        _Pragma("unroll")                                                       \
        for (int p = 0; p < 2; ++p)                                             \
            gload_lds16(_s + (size_t)(p * 64 + srow) * DD + g_glob * 8,         \
                        (char*)Buf[bufi] + p * 8192 + tid * 16);                \
    }

    // counted-vmcnt barrier. sched_barrier(0) pins compute/ds_reads on both
    // sides (rule 18: "memory" clobber alone does not order MFMA/ds_read).
#define SYNC(N)                                                                 \
    {                                                                           \
        __builtin_amdgcn_sched_barrier(0);                                      \
        asm volatile("s_waitcnt vmcnt(" #N ")" ::: "memory");                   \
        __builtin_amdgcn_s_barrier();                                           \
        __builtin_amdgcn_sched_barrier(0);                                      \
    }

    f16x8 af[4][8];   // A fragments: rows wm*64+mi*16+l15, k = j*32+quad*8+e
    f32x4 acc[4][4];
    float rm[4][4];

    // fill af[*][j] from f32 A chunk (in Buf[bufi], rows are chunk-local).
    // Wave's chunk-local row = (wm&1)*64 + mi*16 + l15; row&7 == l15&7.
#define FILL_A(j, bufi)                                                         \
    {                                                                           \
        _Pragma("unroll")                                                       \
        for (int mi = 0; mi < 4; ++mi) {                                        \
            const int row = (wm & 1) * 64 + mi * 16 + l15;                      \
            const int p0  = (2 * quad) ^ (row & 7);                             \
            const int p1  = (2 * quad + 1) ^ (row & 7);                         \
            const f32x4 v0 = *(const f32x4*)((const char*)Buf[bufi] + row * 128 + p0 * 16); \
            const f32x4 v1 = *(const f32x4*)((const char*)Buf[bufi] + row * 128 + p1 * 16); \
            f16x8 o;                                                            \
            o[0] = (_Float16)v0[0]; o[1] = (_Float16)v0[1];                     \
            o[2] = (_Float16)v0[2]; o[3] = (_Float16)v0[3];                     \
            o[4] = (_Float16)v1[0]; o[5] = (_Float16)v1[1];                     \
            o[6] = (_Float16)v1[2]; o[7] = (_Float16)v1[3];                     \
            af[mi][j] = o;                                                      \
        }                                                                       \
    }

#pragma unroll
    for (int mi = 0; mi < 4; ++mi) {
#pragma unroll
        for (int r = 0; r < 4; ++r) rm[mi][r] = -3.4e38f;
#pragma unroll
        for (int ni = 0; ni < 4; ++ni) acc[mi][ni] = (f32x4)0.0f;
    }

    // ---- A prologue: 16 chunks through 4 buffers, uniform SYNC(4).
    // Slot ac: SYNC (chunk ac lands; outstanding was ac..ac+2 = 6 loads);
    // stage ac+3 (A) or B(ac-13) for ac>=13; waves of half (ac>>3) FILL.
    // Handoff: at main-loop entry outstanding = B0,B1,B2 = 6 loads. Buffer
    // reuse is safe: stage at slot ac writes buf (ac+3)&3 = (ac-1)&3, whose
    // ds_reads completed before this slot's barrier.
    STAGE_A(0, 0); STAGE_A(1, 1); STAGE_A(2, 2);
#pragma unroll
    for (int ac = 0; ac < 16; ++ac) {
        SYNC(4);
        if (ac < 13) { STAGE_A(ac + 3, (ac + 3) & 3); }
        else         { STAGE_B(ac - 13, (ac - 13) & 3); }   // B0,B1,B2 -> buf 0,1,2
        if ((wave >> 2) == (ac >> 3)) FILL_A(ac & 7, ac & 3);
    }

    // ---- main: 8 q-tiles x 4 K-chunks (R8-verified). Iter c: SYNC (chunk c
    // lands); stage c+3; compute c. Outstanding at SYNC: c..min(c+2,31).
#pragma unroll 1
    for (int nt = 0; nt < 8; ++nt) {
#pragma unroll
        for (int kc = 0; kc < 4; ++kc) {
            const int c = nt * 4 + kc;
            if (kc < 2)       { SYNC(4); }
            else if (kc == 2) { if (nt < 7) { SYNC(4); } else { SYNC(2); } }
            else              { if (nt < 7) { SYNC(4); } else { SYNC(0); } }

            if (c + 3 < 32) STAGE_B(c + 3, (c + 3) & 3);

            // ds-read this chunk's 8 B fragments (2 ksl x 4 ni)
            f16x8 bfv[2][4];
#pragma unroll
            for (int ksl = 0; ksl < 2; ++ksl)
#pragma unroll
                for (int ni = 0; ni < 4; ++ni) {
                    const int row = wn * 64 + ni * 16 + l15;   // q row 0..127
                    const int pos = (ksl * 4 + quad) ^ (row & 7);
                    bfv[ksl][ni] =
                        *(const f16x8*)((const char*)Buf[kc] + row * 128 + pos * 16);
                }
            __builtin_amdgcn_s_setprio(1);
#pragma unroll
            for (int ksl = 0; ksl < 2; ++ksl)
#pragma unroll
                for (int mi = 0; mi < 4; ++mi)
#pragma unroll
                    for (int ni = 0; ni < 4; ++ni)
                        acc[mi][ni] = __builtin_amdgcn_mfma_f32_16x16x32_f16(
                            af[mi][kc * 2 + ksl], bfv[ksl][ni], acc[mi][ni], 0, 0, 0);
            __builtin_amdgcn_s_setprio(0);
        }
        // fold q-tile into running row max; reset acc
#pragma unroll
        for (int mi = 0; mi < 4; ++mi)
#pragma unroll
            for (int r = 0; r < 4; ++r) {
                rm[mi][r] = fmaxf(rm[mi][r],
                                  fmaxf(fmaxf(acc[mi][0][r], acc[mi][1][r]),
                                        fmaxf(acc[mi][2][r], acc[mi][3][r])));
                acc[mi][0][r] = 0.f; acc[mi][1][r] = 0.f;
                acc[mi][2][r] = 0.f; acc[mi][3][r] = 0.f;
            }
    }

    // ---- epilogue: reduce over the 16 q-col lanes, then the two wn slots
#pragma unroll
    for (int sh = 1; sh <= 8; sh <<= 1)
#pragma unroll
        for (int mi = 0; mi < 4; ++mi)
#pragma unroll
            for (int r = 0; r < 4; ++r)
                rm[mi][r] = fmaxf(rm[mi][r], __shfl_xor(rm[mi][r], sh, 64));

    if (l15 == 0) {
#pragma unroll
        for (int mi = 0; mi < 4; ++mi)
#pragma unroll
            for (int r = 0; r < 4; ++r)
                red[wn][wm * 64 + mi * 16 + quad * 4 + r] = rm[mi][r];
    }
    __syncthreads();
    if (tid < 256)
        scores[(size_t)qh * (B_ * LC) + (size_t)b * LC + mt * 256 + tid] =
            fmaxf(red[0][tid], red[1][tid]);

#undef STAGE_A
#undef STAGE_B
#undef SYNC
#undef FILL_A
}

// Fused softmax-stats + weighted context sum. scores come in two q-half
// buffers; final score = fmax of the two. Each block recomputes M and the
// softmax denominator (16 KB, L2-hit, deterministic -> identical across
// blocks), then accumulates its 64-row chunk of
// out[b][d] = sum_c softmax(scores)[c] * ctx[b][c][d]   (ctx read as f32).
__global__ __launch_bounds__(256)
void out_kernel(const float* __restrict__ scores, const float* __restrict__ ctx,
                float* __restrict__ out) {
    const int ch   = blockIdx.x;   // 0..63
    const int b    = blockIdx.y;   // 0..7
    const int tid  = threadIdx.x;
    const int lane = tid & 63;
    const int wave = tid >> 6;
    __shared__ float smax[4];
    __shared__ float ssum[4];
    __shared__ float pl[64];

    const float* sb0 = scores + (size_t)b * LC;
    const float* sb1 = sb0 + (size_t)B_ * LC;

    float sv[16];
    float lmax = -3.4e38f;
#pragma unroll
    for (int j = 0; j < 16; ++j) {
        const int c = tid + j * 256;
        sv[j] = fmaxf(sb0[c], sb1[c]);
        lmax  = fmaxf(lmax, sv[j]);
    }
    for (int sh = 1; sh < 64; sh <<= 1)
        lmax = fmaxf(lmax, __shfl_xor(lmax, sh, 64));
    if (lane == 0) smax[wave] = lmax;
    __syncthreads();
    const float M = fmaxf(fmaxf(smax[0], smax[1]), fmaxf(smax[2], smax[3]));

    float lsum = 0.f;
#pragma unroll
    for (int j = 0; j < 16; ++j)
        lsum += expf(sv[j] - M);
    for (int sh = 1; sh < 64; sh <<= 1)
        lsum += __shfl_xor(lsum, sh, 64);
    if (lane == 0) ssum[wave] = lsum;
    __syncthreads();
    const float inv = 1.f / (ssum[0] + ssum[1] + ssum[2] + ssum[3]);

    if (tid < 64) {
        const int c = ch * 64 + tid;
        pl[tid] = expf(fmaxf(sb0[c], sb1[c]) - M) * inv;
    }
    __syncthreads();

    const float* cb = ctx + ((size_t)b * LC + (size_t)ch * 64) * DD;
    float acc = 0.f;
#pragma unroll 8
    for (int i = 0; i < 64; ++i)
        acc += pl[i] * cb[(size_t)i * DD + tid];   // coalesced f32
    atomicAdd(&out[b * DD + tid], acc);
}

extern "C" void kernel_launch(void* const* d_in, const int* in_sizes, int n_in,
                              void* d_out, int out_size, void* d_ws, size_t ws_size,
                              hipStream_t stream) {
    const float* q   = (const float*)d_in[0];   // [8, 2048, 256] f32
    const float* ctx = (const float*)d_in[1];   // [8, 4096, 256] f32
    float* out = (float*)d_out;                 // [8, 1, 256] f32

    // ws layout (bytes):
    //   qf     @ 0        : 8*2048*256*2 = 8,388,608
    //   scores @ 8388608  : 2*8*4096*4   =   262,144   (two q-half buffers)
    char* ws = (char*)d_ws;
    _Float16* qf  = (_Float16*)(ws);
    float* scores = (float*)(ws + 8388608);

    convert_q<<<2048, 256, 0, stream>>>(q, qf, out);
    gemm_max_kernel<<<256, 512, 0, stream>>>(qf, ctx, scores);
    out_kernel<<<dim3(64, 8), 256, 0, stream>>>(scores, ctx, out);
}